// Round 1
// baseline (291.397 us; speedup 1.0000x reference)
//
#include <hip/hip_runtime.h>
#include <hip/hip_fp16.h>

// B=4, T=2048, C=1024. Single-head causal attention, fp32 in/out.
// Internals in fp16 (MFMA f32_16x16x32_f16), fp32 accumulation + fp32 softmax.

typedef __attribute__((ext_vector_type(8))) _Float16 half8;
typedef __attribute__((ext_vector_type(4))) _Float16 half4;
typedef __attribute__((ext_vector_type(4))) float f32x4;

#define AS1 __attribute__((address_space(1)))
#define AS3 __attribute__((address_space(3)))

__device__ __forceinline__ void gload_lds16(const void* g, void* l) {
    // async global->LDS, 16B per lane; LDS dest = wave-uniform base + lane*16
    __builtin_amdgcn_global_load_lds((AS1 void*)g, (AS3 void*)l, 16, 0, 0);
}

// ---------------------------------------------------------------------------
// Shared NT-GEMM core: C[128x128] tile, A[m][k] (lda), B[n][k] (ldb), both
// contiguous over k. 256 threads = 4 waves, each wave a 64x64 quadrant,
// 4x4 grid of 16x16x32 MFMAs. K-range [k0,k1), multiples of 32.
// ---------------------------------------------------------------------------
__device__ __forceinline__ void gemm_nt_core(
    const _Float16* __restrict__ A, const _Float16* __restrict__ B,
    int lda, int ldb, int k0, int k1,
    _Float16* ldsA, _Float16* ldsB, f32x4 acc[4][4])
{
    const int t    = threadIdx.x;
    const int lane = t & 63;
    const int wm   = (t >> 7) & 1;
    const int wn   = (t >> 6) & 1;
    const int lr   = lane & 15;
    const int lq   = lane >> 4;

    // staging: 512 chunks of 16B per tile (128 rows x 32 halves), 2 per thread
    const int f0 = t, f1 = t + 256;
    const int r0 = f0 >> 2, h0 = (f0 & 3) * 8;
    const int r1 = f1 >> 2, h1 = (f1 & 3) * 8;
    const _Float16* a0 = A + (size_t)r0 * lda + h0;
    const _Float16* a1 = A + (size_t)r1 * lda + h1;
    const _Float16* b0 = B + (size_t)r0 * ldb + h0;
    const _Float16* b1 = B + (size_t)r1 * ldb + h1;
    _Float16* lA0 = ldsA + f0 * 8;
    _Float16* lA1 = ldsA + f1 * 8;
    _Float16* lB0 = ldsB + f0 * 8;
    _Float16* lB1 = ldsB + f1 * 8;

    for (int k = k0; k < k1; k += 32) {
        __syncthreads();               // prev compute done before overwrite
        gload_lds16(a0 + k, lA0);
        gload_lds16(a1 + k, lA1);
        gload_lds16(b0 + k, lB0);
        gload_lds16(b1 + k, lB1);
        __syncthreads();               // staging visible (compiler adds vmcnt0)

        half8 af[4], bf[4];
#pragma unroll
        for (int i = 0; i < 4; ++i) {
            af[i] = *(const half8*)(ldsA + ((wm * 64 + i * 16 + lr) * 32 + lq * 8));
            bf[i] = *(const half8*)(ldsB + ((wn * 64 + i * 16 + lr) * 32 + lq * 8));
        }
#pragma unroll
        for (int mi = 0; mi < 4; ++mi)
#pragma unroll
            for (int ni = 0; ni < 4; ++ni)
                acc[mi][ni] = __builtin_amdgcn_mfma_f32_16x16x32_f16(
                    af[mi], bf[ni], acc[mi][ni], 0, 0, 0);
    }
}

// ---------------------------------------------------------------------------
// fp32 -> fp16 convert (n multiple of 4)
// ---------------------------------------------------------------------------
__global__ __launch_bounds__(256) void f32tof16_k(
    const float* __restrict__ in, _Float16* __restrict__ out, int n)
{
    int i = (blockIdx.x * 256 + threadIdx.x) * 4;
    if (i < n) {
        float4 f = *(const float4*)(in + i);
        half4 h = { (_Float16)f.x, (_Float16)f.y, (_Float16)f.z, (_Float16)f.w };
        *(half4*)(out + i) = h;
    }
}

// ---------------------------------------------------------------------------
// QKV: out = x @ W^T. z selects {Q, K, Vt}. Vt stored transposed per batch:
// Vt[b][d][t], so PV is NT-form too.
// ---------------------------------------------------------------------------
__global__ __launch_bounds__(256) void qkv_gemm_k(
    const _Float16* __restrict__ xh, const _Float16* __restrict__ Wh,
    _Float16* __restrict__ Q, _Float16* __restrict__ K, _Float16* __restrict__ Vt)
{
    __shared__ __align__(16) _Float16 ldsA[128 * 32];
    __shared__ __align__(16) _Float16 ldsB[128 * 32];
    const int tileM = blockIdx.x * 128;
    const int tileN = blockIdx.y * 128;
    const int z     = blockIdx.z;
    const _Float16* W = Wh + (size_t)z * 1024 * 1024;

    f32x4 acc[4][4] = {};
    gemm_nt_core(xh + (size_t)tileM * 1024, W + (size_t)tileN * 1024,
                 1024, 1024, 0, 1024, ldsA, ldsB, acc);

    const int lane = threadIdx.x & 63;
    const int wm = (threadIdx.x >> 7) & 1, wn = (threadIdx.x >> 6) & 1;
    const int lr = lane & 15, lq = lane >> 4;

    if (z == 2) {
#pragma unroll
        for (int mi = 0; mi < 4; ++mi)
#pragma unroll
            for (int ni = 0; ni < 4; ++ni) {
                int m0 = tileM + wm * 64 + mi * 16 + lq * 4;   // 4 consecutive t
                int n  = tileN + wn * 64 + ni * 16 + lr;       // d
                int b = m0 >> 11, tt = m0 & 2047;
                half4 h = { (_Float16)acc[mi][ni][0], (_Float16)acc[mi][ni][1],
                            (_Float16)acc[mi][ni][2], (_Float16)acc[mi][ni][3] };
                *(half4*)(Vt + (size_t)b * 2048 * 1024 + (size_t)n * 2048 + tt) = h;
            }
    } else {
        _Float16* O = (z == 0) ? Q : K;
#pragma unroll
        for (int mi = 0; mi < 4; ++mi)
#pragma unroll
            for (int ni = 0; ni < 4; ++ni) {
                int m0 = tileM + wm * 64 + mi * 16 + lq * 4;
                int n  = tileN + wn * 64 + ni * 16 + lr;
#pragma unroll
                for (int r = 0; r < 4; ++r)
                    O[(size_t)(m0 + r) * 1024 + n] = (_Float16)acc[mi][ni][r];
            }
    }
}

// ---------------------------------------------------------------------------
// Scores: S[b][t][s] = scale * (Q[b,t,:] . K[b,s,:]); skip fully-masked tiles,
// write only s <= t (softmax never reads s > t).
// ---------------------------------------------------------------------------
__global__ __launch_bounds__(256) void scores_gemm_k(
    const _Float16* __restrict__ Q, const _Float16* __restrict__ K,
    float* __restrict__ S)
{
    const int tileT = blockIdx.x * 128;
    const int tileS = blockIdx.y * 128;
    if (tileS > tileT + 127) return;   // fully above diagonal
    const int b = blockIdx.z;

    __shared__ __align__(16) _Float16 ldsA[128 * 32];
    __shared__ __align__(16) _Float16 ldsB[128 * 32];
    f32x4 acc[4][4] = {};
    gemm_nt_core(Q + (size_t)b * 2048 * 1024 + (size_t)tileT * 1024,
                 K + (size_t)b * 2048 * 1024 + (size_t)tileS * 1024,
                 1024, 1024, 0, 1024, ldsA, ldsB, acc);

    const int lane = threadIdx.x & 63;
    const int wm = (threadIdx.x >> 7) & 1, wn = (threadIdx.x >> 6) & 1;
    const int lr = lane & 15, lq = lane >> 4;
    const float scale = 0.03125f;  // 1024^-0.5

#pragma unroll
    for (int mi = 0; mi < 4; ++mi)
#pragma unroll
        for (int ni = 0; ni < 4; ++ni) {
            int t0 = tileT + wm * 64 + mi * 16 + lq * 4;
            int ss = tileS + wn * 64 + ni * 16 + lr;
#pragma unroll
            for (int r = 0; r < 4; ++r) {
                int tt = t0 + r;
                if (ss <= tt)
                    S[((size_t)b * 2048 + tt) * 2048 + ss] = acc[mi][ni][r] * scale;
            }
        }
}

// ---------------------------------------------------------------------------
// Softmax over row [0..t]; writes fp16 P IN-PLACE over the fp32 S row
// (P row stride = 4096 halves). Zeros for s > t. All reads complete before
// the block's reduction barriers, so in-place is race-free.
// ---------------------------------------------------------------------------
__global__ __launch_bounds__(256) void softmax_k(
    const float* __restrict__ S, _Float16* __restrict__ P)
{
    const int t = blockIdx.x, b = blockIdx.y;
    const float*  row  = S + ((size_t)b * 2048 + t) * 2048;
    _Float16*     prow = P + ((size_t)b * 2048 + t) * 4096;
    const int len = t + 1;
    const int tid = threadIdx.x;

    float v[8];
    int cnt = 0;
    float mx = -1e30f;
    for (int s = tid; s < len; s += 256) {
        float x = row[s];
        v[cnt++] = x;
        mx = fmaxf(mx, x);
    }
    __shared__ float wred[4];
#pragma unroll
    for (int o = 32; o > 0; o >>= 1) mx = fmaxf(mx, __shfl_xor(mx, o));
    if ((tid & 63) == 0) wred[tid >> 6] = mx;
    __syncthreads();
    mx = fmaxf(fmaxf(wred[0], wred[1]), fmaxf(wred[2], wred[3]));

    float sum = 0.f;
    for (int i = 0; i < cnt; ++i) {
        float e = __expf(v[i] - mx);
        v[i] = e;
        sum += e;
    }
#pragma unroll
    for (int o = 32; o > 0; o >>= 1) sum += __shfl_xor(sum, o);
    __shared__ float wsum[4];
    if ((tid & 63) == 0) wsum[tid >> 6] = sum;
    __syncthreads();
    sum = wsum[0] + wsum[1] + wsum[2] + wsum[3];
    const float inv = 1.0f / sum;

    cnt = 0;
    for (int s = tid; s < len; s += 256) prow[s] = (_Float16)(v[cnt++] * inv);
    for (int s = tid; s < 2048; s += 256)
        if (s >= len) prow[s] = (_Float16)0.f;
}

// ---------------------------------------------------------------------------
// PV: out[b][t][d] = sum_s P[b][t][s] * Vt[b][d][s]. P rows live in the S
// buffer (stride 4096 halves). K-loop limited to t0+128 (P zero beyond).
// ---------------------------------------------------------------------------
__global__ __launch_bounds__(256) void pv_gemm_k(
    const _Float16* __restrict__ P, const _Float16* __restrict__ Vt,
    float* __restrict__ out)
{
    __shared__ __align__(16) _Float16 ldsA[128 * 32];
    __shared__ __align__(16) _Float16 ldsB[128 * 32];
    const int tileT = blockIdx.x * 128;
    const int tileD = blockIdx.y * 128;
    const int b     = blockIdx.z;
    const int kEnd  = tileT + 128;   // causal: s <= t < tileT+128

    f32x4 acc[4][4] = {};
    gemm_nt_core(P + ((size_t)b * 2048 + tileT) * 4096,
                 Vt + (size_t)b * 1024 * 2048 + (size_t)tileD * 2048,
                 4096, 2048, 0, kEnd, ldsA, ldsB, acc);

    const int lane = threadIdx.x & 63;
    const int wm = (threadIdx.x >> 7) & 1, wn = (threadIdx.x >> 6) & 1;
    const int lr = lane & 15, lq = lane >> 4;

#pragma unroll
    for (int mi = 0; mi < 4; ++mi)
#pragma unroll
        for (int ni = 0; ni < 4; ++ni) {
            int t0 = tileT + wm * 64 + mi * 16 + lq * 4;
            int dd = tileD + wn * 64 + ni * 16 + lr;
#pragma unroll
            for (int r = 0; r < 4; ++r)
                out[((size_t)b * 2048 + (t0 + r)) * 1024 + dd] = acc[mi][ni][r];
        }
}

// ---------------------------------------------------------------------------
extern "C" void kernel_launch(void* const* d_in, const int* in_sizes, int n_in,
                              void* d_out, int out_size, void* d_ws, size_t ws_size,
                              hipStream_t stream)
{
    const float* x  = (const float*)d_in[0];
    const float* Wq = (const float*)d_in[1];
    const float* Wk = (const float*)d_in[2];
    const float* Wv = (const float*)d_in[3];
    float* out = (float*)d_out;

    char* ws = (char*)d_ws;
    // layout (MB offsets): xh 0..16 | Wh 16..22 | Q 22..38 | K 38..54 |
    // Vt 54..70 | S 70..134 (P aliased into S).  Total 134 MB.
    _Float16* xh = (_Float16*)(ws);
    _Float16* Wh = (_Float16*)(ws + (16u << 20));
    _Float16* Qh = (_Float16*)(ws + (22u << 20));
    _Float16* Kh = (_Float16*)(ws + (38u << 20));
    _Float16* Vt = (_Float16*)(ws + (54u << 20));
    float*    S  = (float*)   (ws + (70u << 20));
    _Float16* P  = (_Float16*)S;   // softmax writes fp16 in-place, stride 4096

    // converts
    f32tof16_k<<<8192, 256, 0, stream>>>(x, xh, 4 * 2048 * 1024);
    f32tof16_k<<<1024, 256, 0, stream>>>(Wq, Wh,                1024 * 1024);
    f32tof16_k<<<1024, 256, 0, stream>>>(Wk, Wh + 1024 * 1024,  1024 * 1024);
    f32tof16_k<<<1024, 256, 0, stream>>>(Wv, Wh + 2048 * 1024,  1024 * 1024);

    // QKV projections (z: 0=Q, 1=K, 2=V-transposed)
    qkv_gemm_k<<<dim3(64, 8, 3), 256, 0, stream>>>(xh, Wh, Qh, Kh, Vt);

    // causal scores
    scores_gemm_k<<<dim3(16, 16, 4), 256, 0, stream>>>(Qh, Kh, S);

    // softmax (one block per row)
    softmax_k<<<dim3(2048, 4), 256, 0, stream>>>(S, P);

    // out = P @ V
    pv_gemm_k<<<dim3(16, 8, 4), 256, 0, stream>>>(P, Vt, out);
}